// Round 14
// baseline (583.398 us; speedup 1.0000x reference)
//
#include <hip/hip_runtime.h>

// SVF scaling-and-squaring: 16 steps of warp <- warp + sample(warp, id + warp)
// Brick layout: float index of voxel (x,y,z) =
//   ((((z>>1)*80 + (y>>1))*160 + x)*4 + ((z&1)*2 + (y&1))) * 3
// r13 structure (copy + 15 brick steps + coalesced final). This round:
// channels 0-1 of the trilinear interp are computed as f32x2 ext-vectors so
// clang emits packed v_pk_fma_f32/v_pk_mul_f32 (CDNA4 2-wide fp32), and the
// corner row addressing uses y*960-(y&1)*957 / z*76800-(z&1)*76794 (mad form).
// Ruled out by measurement: NT stores (r5), LDS gather (r9), 2 voxels/thread
// (r8), asm-forced 8-load MLP (r10/11), 640-thread SALU decode (r12).
// Late steps sit at the L1-line transaction floor (~43 us); mid steps are
// ~half VALU -- this targets that half.

constexpr int S   = 160;
constexpr int VOX = S * S * S;        // 4,096,000
constexpr int THREADS = 256;
constexpr int BLOCKS  = VOX / THREADS;   // 16000
constexpr int NXCD  = 8;
constexpr int CHUNK = BLOCKS / NXCD;     // 2000

typedef float f32x2 __attribute__((ext_vector_type(2)));
typedef float f32x4 __attribute__((ext_vector_type(4)));

__device__ __forceinline__ float idcoord(int u) {
    // matches jnp: (2.0*arange + 1.0)/160.0 - 1.0 in fp32
    return (2.0f * (float)u + 1.0f) / 160.0f - 1.0f;
}

__device__ __forceinline__ f32x4 ld4v(const float* p) { f32x4 r; __builtin_memcpy(&r, p, 16); return r; }

// brick float-index of voxel (x,y,z)
__device__ __forceinline__ int brickf(int x, int y, int z) {
    return ((((z >> 1) * 80 + (y >> 1)) * S + x) * 4 + ((z & 1) * 2 + (y & 1))) * 3;
}

// shared gather: 8 corner rows from brick layout + trilinear combine.
// Channels 0-1 packed (f32x2 -> v_pk_* ops), channel 2 scalar.
__device__ __forceinline__ void brick_gather(const float* __restrict__ src,
                                             int x, int y, int z,
                                             float w0, float w1, float w2,
                                             float& n0, float& n1, float& n2) {
    float gx = fminf(fmaxf(fmaf(80.0f, w0, (float)x), 0.0f), 159.0f);
    float gy = fminf(fmaxf(fmaf(80.0f, w1, (float)y), 0.0f), 159.0f);
    float gz = fminf(fmaxf(fmaf(80.0f, w2, (float)z), 0.0f), 159.0f);

    const float x0f = floorf(gx), y0f = floorf(gy), z0f = floorf(gz);
    const float fx = gx - x0f, fy = gy - y0f, fz = gz - z0f;
    const int x0 = (int)x0f, y0 = (int)y0f, z0 = (int)z0f;
    const int x1 = min(x0 + 1, S - 1);
    const int y1 = min(y0 + 1, S - 1);
    const int z1 = min(z0 + 1, S - 1);
    const float ofx = 1.0f - fx, ofy = 1.0f - fy, ofz = 1.0f - fz;

    // row bases, mad form: Y = y*960 - (y&1)*957 ; Z = z*76800 - (z&1)*76794
    const int Y0 = y0 * 960 - (y0 & 1) * 957;
    const int Y1 = y1 * 960 - (y1 & 1) * 957;
    const int Z0 = z0 * 76800 - (z0 & 1) * 76794;
    const int Z1 = z1 * 76800 - (z1 & 1) * 76794;
    const int rb4[4] = { Z0 + Y0, Z0 + Y1, Z1 + Y0, Z1 + Y1 };

    const int xo0 = x0 * 12, xo1 = x1 * 12;
    f32x2 g01[4];
    float g2[4];
    #pragma unroll
    for (int q = 0; q < 4; ++q) {
        f32x4 A = ld4v(src + rb4[q] + xo0);
        f32x4 B = ld4v(src + rb4[q] + xo1);
        g01[q] = A.xy * ofx + B.xy * fx;      // packed fp32
        g2[q]  = A.z  * ofx + B.z  * fx;
    }
    f32x2 r01 = (g01[0] * ofy + g01[1] * fy) * ofz
              + (g01[2] * ofy + g01[3] * fy) * fz;
    float r2  = (g2[0]  * ofy + g2[1]  * fy) * ofz
              + (g2[2]  * ofy + g2[3]  * fy) * fz;

    n0 = w0 + r01.x;
    n1 = w1 + r01.y;
    n2 = w2 + r2;
}

// Copy: v planar -> brick, scaled by 2^-16 (exact). 32x4x2 tile per block.
__global__ __launch_bounds__(THREADS) void svf_copy(const float* __restrict__ src,
                                                    float* __restrict__ dst,
                                                    float scale) {
    const int b   = blockIdx.x;
    const int blk = (b & (NXCD - 1)) * CHUNK + (b >> 3);
    const int bx = blk % 5;
    const int by = (blk / 5) % 40;
    const int bz = blk / 200;

    const int tid = threadIdx.x;
    const int x = bx * 32 + (tid & 31);
    const int y = by * 4 + ((tid >> 5) & 3);
    const int z = bz * 2 + (tid >> 7);

    const int idx = (z * S + y) * S + x;
    const float w0 = src[idx] * scale;
    const float w1 = src[idx + VOX] * scale;
    const float w2 = src[idx + 2 * VOX] * scale;

    const int f = brickf(x, y, z);
    float2 st = make_float2(w0, w1);
    __builtin_memcpy(dst + f, &st, 8);
    dst[f + 2] = w2;
}

// Mid step: brick -> brick, brick-linear thread order.
__global__ __launch_bounds__(THREADS) void svf_step(const float* __restrict__ src,
                                                    float* __restrict__ dst) {
    const int b   = blockIdx.x;
    const int blk = (b & (NXCD - 1)) * CHUNK + (b >> 3);
    const int m   = blk * THREADS + threadIdx.x;   // brick-linear voxel id

    const int lr = m & 3;
    const int t  = m >> 2;
    const int x  = t % S;
    const int u  = t / S;
    const int y  = (u % 80) * 2 + (lr & 1);
    const int z  = (u / 80) * 2 + (lr >> 1);

    const int f = m * 3;

    f32x4 own = ld4v(src + f);
    float n0, n1, n2;
    brick_gather(src, x, y, z, own.x, own.y, own.z, n0, n1, n2);

    f32x2 st; st.x = n0; st.y = n1;
    __builtin_memcpy(dst + f, &st, 8);
    dst[f + 2] = n2;
}

// Final step: brick src -> planar dst + identity. Planar 32x4x2 tile mapping
// so planar stores are coalesced.
__global__ __launch_bounds__(THREADS) void svf_final(const float* __restrict__ src,
                                                     float* __restrict__ dst) {
    const int b   = blockIdx.x;
    const int blk = (b & (NXCD - 1)) * CHUNK + (b >> 3);
    const int bx = blk % 5;
    const int by = (blk / 5) % 40;
    const int bz = blk / 200;

    const int tid = threadIdx.x;
    const int x = bx * 32 + (tid & 31);
    const int y = by * 4 + ((tid >> 5) & 3);
    const int z = bz * 2 + (tid >> 7);

    const int f = brickf(x, y, z);
    f32x4 own = ld4v(src + f);
    float n0, n1, n2;
    brick_gather(src, x, y, z, own.x, own.y, own.z, n0, n1, n2);

    const int pidx = (z * S + y) * S + x;
    dst[pidx]           = idcoord(x) + n0;
    dst[pidx + VOX]     = idcoord(y) + n1;
    dst[pidx + 2 * VOX] = idcoord(z) + n2;
}

extern "C" void kernel_launch(void* const* d_in, const int* in_sizes, int n_in,
                              void* d_out, int out_size, void* d_ws, size_t ws_size,
                              hipStream_t stream) {
    // in[0] = identity_grid (recomputed analytically), in[1] = v
    const float* v = (const float*)d_in[1];
    float* out = (float*)d_out;
    float* ws  = (float*)d_ws;   // 3*160^3*4 = 49.15 MB used

    const float s = 1.0f / 65536.0f;  // 2^-16, exact

    // init: v (planar, scaled) -> out used as brick scratch
    svf_copy<<<BLOCKS, THREADS, 0, stream>>>(v, out, s);
    // steps 1..15: ping-pong; odd step -> ws, even step -> out.
    // step 15 lands in ws, so the final pass reads ws and writes out (planar).
    for (int k = 1; k <= 15; ++k) {
        if (k & 1)
            svf_step<<<BLOCKS, THREADS, 0, stream>>>(out, ws);
        else
            svf_step<<<BLOCKS, THREADS, 0, stream>>>(ws, out);
    }
    // step 16: ws (brick) -> d_out planar + identity
    svf_final<<<BLOCKS, THREADS, 0, stream>>>(ws, out);
}

// Round 15
// 557.674 us; speedup vs baseline: 1.0461x; 1.0461x over previous
//
#include <hip/hip_runtime.h>

// SVF scaling-and-squaring: 16 steps of warp <- warp + sample(warp, id + warp)
// Brick layout: float index of voxel (x,y,z) =
//   ((((z>>1)*80 + (y>>1))*160 + x)*4 + ((z&1)*2 + (y&1))) * 3
// r13 structure: copy + 15 brick steps (256-thread, XCD-chunked) + final with
// planar-coalesced stores. Measured best: 558.9 us.
// Ruled out by measurement: NT stores (r5), LDS gather (r9), 2 voxels/thread
// (r8), asm-forced 8-load MLP (r10/11), 640-thread SALU decode (r12),
// packed f32x2 interp (r14). Late steps sit at the L1 transaction floor
// (~43 us for 8 random 16B gathers/voxel); mid steps are latency/issue mixed
// at ~2x the streaming-BW floor.

constexpr int S   = 160;
constexpr int VOX = S * S * S;        // 4,096,000
constexpr int THREADS = 256;
constexpr int BLOCKS  = VOX / THREADS;   // 16000
constexpr int NXCD  = 8;
constexpr int CHUNK = BLOCKS / NXCD;     // 2000

__device__ __forceinline__ float idcoord(int u) {
    // matches jnp: (2.0*arange + 1.0)/160.0 - 1.0 in fp32
    return (2.0f * (float)u + 1.0f) / 160.0f - 1.0f;
}

__device__ __forceinline__ float4 ld4u(const float* p) { float4 r; __builtin_memcpy(&r, p, 16); return r; }

// brick float-index of voxel (x,y,z)
__device__ __forceinline__ int brickf(int x, int y, int z) {
    return ((((z >> 1) * 80 + (y >> 1)) * S + x) * 4 + ((z & 1) * 2 + (y & 1))) * 3;
}

// shared gather: 8 corner rows from brick layout + trilinear combine
__device__ __forceinline__ void brick_gather(const float* __restrict__ src,
                                             int x, int y, int z,
                                             float w0, float w1, float w2,
                                             float& n0, float& n1, float& n2) {
    float gx = fminf(fmaxf(fmaf(80.0f, w0, (float)x), 0.0f), 159.0f);
    float gy = fminf(fmaxf(fmaf(80.0f, w1, (float)y), 0.0f), 159.0f);
    float gz = fminf(fmaxf(fmaf(80.0f, w2, (float)z), 0.0f), 159.0f);

    const float x0f = floorf(gx), y0f = floorf(gy), z0f = floorf(gz);
    const float fx = gx - x0f, fy = gy - y0f, fz = gz - z0f;
    const int x0 = (int)x0f, y0 = (int)y0f, z0 = (int)z0f;
    const int x1 = min(x0 + 1, S - 1);
    const int y1 = min(y0 + 1, S - 1);
    const int z1 = min(z0 + 1, S - 1);
    const float ofx = 1.0f - fx, ofy = 1.0f - fy, ofz = 1.0f - fz;

    const int Y0 = (y0 >> 1) * 1920 + (y0 & 1) * 3;   // 1920 = 160*4*3
    const int Y1 = (y1 >> 1) * 1920 + (y1 & 1) * 3;
    const int Z0 = (z0 >> 1) * 153600 + (z0 & 1) * 6; // 153600 = 80*160*4*3
    const int Z1 = (z1 >> 1) * 153600 + (z1 & 1) * 6;
    const int rb4[4] = { Z0 + Y0, Z0 + Y1, Z1 + Y0, Z1 + Y1 };

    const int xo0 = x0 * 12, xo1 = x1 * 12;
    float g0[4], g1[4], g2[4];
    #pragma unroll
    for (int q = 0; q < 4; ++q) {
        float4 A = ld4u(src + rb4[q] + xo0);
        float4 B = ld4u(src + rb4[q] + xo1);
        g0[q] = A.x * ofx + B.x * fx;
        g1[q] = A.y * ofx + B.y * fx;
        g2[q] = A.z * ofx + B.z * fx;
    }
    float r0 = (g0[0] * ofy + g0[1] * fy) * ofz + (g0[2] * ofy + g0[3] * fy) * fz;
    float r1 = (g1[0] * ofy + g1[1] * fy) * ofz + (g1[2] * ofy + g1[3] * fy) * fz;
    float r2 = (g2[0] * ofy + g2[1] * fy) * ofz + (g2[2] * ofy + g2[3] * fy) * fz;

    n0 = w0 + r0;
    n1 = w1 + r1;
    n2 = w2 + r2;
}

// Copy: v planar -> brick, scaled by 2^-16 (exact). 32x4x2 tile per block.
__global__ __launch_bounds__(THREADS) void svf_copy(const float* __restrict__ src,
                                                    float* __restrict__ dst,
                                                    float scale) {
    const int b   = blockIdx.x;
    const int blk = (b & (NXCD - 1)) * CHUNK + (b >> 3);
    const int bx = blk % 5;
    const int by = (blk / 5) % 40;
    const int bz = blk / 200;

    const int tid = threadIdx.x;
    const int x = bx * 32 + (tid & 31);
    const int y = by * 4 + ((tid >> 5) & 3);
    const int z = bz * 2 + (tid >> 7);

    const int idx = (z * S + y) * S + x;
    const float w0 = src[idx] * scale;
    const float w1 = src[idx + VOX] * scale;
    const float w2 = src[idx + 2 * VOX] * scale;

    const int f = brickf(x, y, z);
    float2 st = make_float2(w0, w1);
    __builtin_memcpy(dst + f, &st, 8);
    dst[f + 2] = w2;
}

// Mid step: brick -> brick, brick-linear thread order (r7-proven).
__global__ __launch_bounds__(THREADS) void svf_step(const float* __restrict__ src,
                                                    float* __restrict__ dst) {
    const int b   = blockIdx.x;
    const int blk = (b & (NXCD - 1)) * CHUNK + (b >> 3);
    const int m   = blk * THREADS + threadIdx.x;   // brick-linear voxel id

    const int lr = m & 3;
    const int t  = m >> 2;
    const int x  = t % S;
    const int u  = t / S;
    const int y  = (u % 80) * 2 + (lr & 1);
    const int z  = (u / 80) * 2 + (lr >> 1);

    const int f = m * 3;

    float4 own = ld4u(src + f);
    float n0, n1, n2;
    brick_gather(src, x, y, z, own.x, own.y, own.z, n0, n1, n2);

    float2 st = make_float2(n0, n1);
    __builtin_memcpy(dst + f, &st, 8);
    dst[f + 2] = n2;
}

// Final step: brick src -> planar dst + identity. Planar 32x4x2 tile mapping
// (copy-style) so planar stores are coalesced.
__global__ __launch_bounds__(THREADS) void svf_final(const float* __restrict__ src,
                                                     float* __restrict__ dst) {
    const int b   = blockIdx.x;
    const int blk = (b & (NXCD - 1)) * CHUNK + (b >> 3);
    const int bx = blk % 5;
    const int by = (blk / 5) % 40;
    const int bz = blk / 200;

    const int tid = threadIdx.x;
    const int x = bx * 32 + (tid & 31);
    const int y = by * 4 + ((tid >> 5) & 3);
    const int z = bz * 2 + (tid >> 7);

    const int f = brickf(x, y, z);
    float4 own = ld4u(src + f);
    float n0, n1, n2;
    brick_gather(src, x, y, z, own.x, own.y, own.z, n0, n1, n2);

    const int pidx = (z * S + y) * S + x;
    dst[pidx]           = idcoord(x) + n0;
    dst[pidx + VOX]     = idcoord(y) + n1;
    dst[pidx + 2 * VOX] = idcoord(z) + n2;
}

extern "C" void kernel_launch(void* const* d_in, const int* in_sizes, int n_in,
                              void* d_out, int out_size, void* d_ws, size_t ws_size,
                              hipStream_t stream) {
    // in[0] = identity_grid (recomputed analytically), in[1] = v
    const float* v = (const float*)d_in[1];
    float* out = (float*)d_out;
    float* ws  = (float*)d_ws;   // 3*160^3*4 = 49.15 MB used

    const float s = 1.0f / 65536.0f;  // 2^-16, exact

    // init: v (planar, scaled) -> out used as brick scratch
    svf_copy<<<BLOCKS, THREADS, 0, stream>>>(v, out, s);
    // steps 1..15: ping-pong; odd step -> ws, even step -> out.
    // step 15 lands in ws, so the final pass reads ws and writes out (planar).
    for (int k = 1; k <= 15; ++k) {
        if (k & 1)
            svf_step<<<BLOCKS, THREADS, 0, stream>>>(out, ws);
        else
            svf_step<<<BLOCKS, THREADS, 0, stream>>>(ws, out);
    }
    // step 16: ws (brick) -> d_out planar + identity
    svf_final<<<BLOCKS, THREADS, 0, stream>>>(ws, out);
}